// Round 3
// baseline (324.557 us; speedup 1.0000x reference)
//
#include <hip/hip_runtime.h>

#define E_EDGES   1000000
#define NNODES    2048
#define DLAT      64
#define HCH       128
#define KP        136            // w1t row stride in bf16 (global memory layout only)
#define TILE      64
#define NTILES    (E_EDGES / TILE)   // 15625 exact
#define NSPREAD   8
#define GRID_GEMM 2048
#define ZVEC      (32 * 2048 * 64 / 4)   // 1048576 float4s
#define ZBLK      2048

typedef short  shortx8 __attribute__((ext_vector_type(8)));
typedef float  floatx4 __attribute__((ext_vector_type(4)));

__device__ __forceinline__ unsigned short f2bf(float f) {
  union { float f; unsigned int u; } v; v.f = f;
  unsigned int r = (v.u + 0x7fffu + ((v.u >> 16) & 1u)) >> 16;
  return (unsigned short)r;
}

__device__ __forceinline__ void cfence() { asm volatile("" ::: "memory"); }

// pack attr floats -> [bf(a0),bf(a1),bf(a2),bf(a3),bf16(1.0),0,0,0] as uint4
__device__ __forceinline__ uint4 attr_pack(float4 a) {
  uint4 w;
  w.x = (unsigned)f2bf(a.x) | ((unsigned)f2bf(a.y) << 16);
  w.y = (unsigned)f2bf(a.z) | ((unsigned)f2bf(a.w) << 16);
  w.z = 0x3F80u;   // bf16(1.0) in low half (bias lane), 0 in high
  w.w = 0u;
  return w;
}

__device__ __forceinline__ unsigned pack_rows(int s, int d) {
  unsigned rs = (unsigned)s & 0xFFFFu;
  unsigned rd = (unsigned)(((s & ~(NNODES - 1)) | (d & (NNODES - 1)))) & 0xFFFFu; // dst uses src batch
  return rs | (rd << 16);
}

// ---------------------------------------------------------------- prep ----
__global__ void k_prep(const float* __restrict__ z, const float* __restrict__ W1,
                       const float* __restrict__ b1,
                       unsigned short* __restrict__ zb, unsigned short* __restrict__ w1t,
                       float* __restrict__ gstats) {
  int bid = blockIdx.x;
  if (bid < ZBLK) {
    const float4* z4 = (const float4*)z;
    ushort4* zb4 = (ushort4*)zb;
    for (int i = bid * 256 + threadIdx.x; i < ZVEC; i += ZBLK * 256) {
      float4 v = z4[i];
      ushort4 o;
      o.x = f2bf(v.x); o.y = f2bf(v.y); o.z = f2bf(v.z); o.w = f2bf(v.w);
      zb4[i] = o;
    }
  } else if (bid == ZBLK) {
    // W1T[n][k] = W1[k][n] for k<132, b1[n] at k=132, 0 for k in 133..135
    for (int idx = threadIdx.x; idx < 132 * HCH; idx += 256) {
      int k = idx >> 7, n = idx & 127;              // coalesced read of W1
      w1t[n * KP + k] = f2bf(W1[idx]);
    }
    for (int idx = threadIdx.x; idx < HCH * (KP - 132); idx += 256) {
      int n = idx / (KP - 132);
      int k = 132 + (idx - n * (KP - 132));
      w1t[n * KP + k] = (k == 132) ? f2bf(b1[n]) : (unsigned short)0;
    }
  } else {
    for (int i = threadIdx.x; i < NSPREAD * 2 * HCH; i += 256) gstats[i] = 0.f;
  }
}

// ---------------------------------------------------------------- gemm ----
// global_load_lds staging (no VGPR round-trip), XOR-swizzled A (256B rows),
// double-buffered LDS, loads issued at body top -> vmcnt(0) publish is cheap
// and safe. 4 waves in 2x2: wave=(eh,nh): edges eh*32..+31, ch nh*64..+63.
template<bool OUT>
__global__ __launch_bounds__(256, 3)
void k_gemm(const unsigned short* __restrict__ zb,
            const unsigned short* __restrict__ w1t,
            const int* __restrict__ ei,
            const float* __restrict__ attr,
            float* __restrict__ gstats,
            const float* __restrict__ gamma,
            const float* __restrict__ beta,
            const float* __restrict__ W2,
            const float* __restrict__ b2,
            float* __restrict__ out) {
  __shared__ __align__(16) unsigned short A[2 * TILE * 128];     // 32768 B
  __shared__ __align__(16) unsigned short attrB[2 * TILE * 8];   //  2048 B
  __shared__ float s_sum[HCH], s_sq[HCH];
  __shared__ float po[2][TILE];

  const int tid  = threadIdx.x;
  const int lane = tid & 63;
  const int wave = tid >> 6;
  const int l15  = lane & 15;
  const int quad = lane >> 4;
  const int eh   = wave >> 1;
  const int nh   = wave & 1;
  const int e    = tid >> 2;     // this thread's own edge within tile
  const int q    = tid & 3;
  const int grid = GRID_GEMM;

  // stage one 64-edge tile into A[dst] via 4 global_load_lds per wave.
  // physical slot s of row e holds logical 16B chunk g = s ^ (e&7)
  // (linear LDS dest, pre-swizzled global source — guide rule 21).
  auto glds_tile = [&](unsigned prow, int dst) {
#pragma unroll
    for (int c = 0; c < 4; ++c) {
      unsigned p = (unsigned)__shfl((int)prow, c * 16 + ((lane >> 4) << 2));
      int e7 = (c * 4 + (lane >> 4)) & 7;
      int g  = (lane & 15) ^ e7;
      unsigned row = (g < 8) ? (p & 0xFFFFu) : (p >> 16);
      const unsigned short* ga = zb + ((size_t)row << 6) + ((unsigned)(g & 7) << 3);
      unsigned short* la = (unsigned short*)A + dst * (TILE * 128) + wave * 2048 + c * 512;
      __builtin_amdgcn_global_load_lds(
          (const __attribute__((address_space(1))) unsigned int*)ga,
          (__attribute__((address_space(3))) unsigned int*)la, 16, 0, 0);
    }
  };

  // ---- B fragments in registers
  shortx8 bfr[4][4], bfr4[4];
#pragma unroll
  for (int nt = 0; nt < 4; ++nt) {
    const unsigned short* bp = w1t + (nh * 64 + nt * 16 + l15) * KP;
#pragma unroll
    for (int kk = 0; kk < 4; ++kk)
      bfr[nt][kk] = *(const shortx8*)(bp + kk * 32 + quad * 8);
    bfr4[nt] = *(const shortx8*)(bp + 128);   // k=128..135 (attr rows + bias); A=0 on quads 1-3
  }

  float ea[4], ebb[4], ew2[4], b2v = 0.f;
  float ssum[4] = {0.f, 0.f, 0.f, 0.f}, ssq[4] = {0.f, 0.f, 0.f, 0.f};
  if (OUT) {
#pragma unroll
    for (int nt = 0; nt < 4; ++nt) {
      int c = nh * 64 + nt * 16 + l15;
      float S = 0.f, Q = 0.f;
#pragma unroll
      for (int i = 0; i < NSPREAD; ++i) {
        S += gstats[i * 2 * HCH + c];
        Q += gstats[i * 2 * HCH + HCH + c];
      }
      float mu   = S * (1.0f / (float)E_EDGES);
      float var  = Q * (1.0f / (float)E_EDGES) - mu * mu;
      float rstd = rsqrtf(var + 1e-5f);
      float a = gamma[c] * rstd;
      ea[nt]  = a;
      ebb[nt] = beta[c] - mu * a;
      ew2[nt] = W2[c];
    }
    b2v = b2[0];
  } else {
    if (tid < HCH) { s_sum[tid] = 0.f; s_sq[tid] = 0.f; }
  }

  // ---- prologue: stage t0, prefetch t1 state, issue t2 loads
  const int t0 = blockIdx.x;
  int tA = t0 + grid;      if (tA > NTILES - 1) tA = NTILES - 1;
  int tB = t0 + 2 * grid;  if (tB > NTILES - 1) tB = NTILES - 1;

  unsigned prow1;          // rows of next tile (t+1)
  uint4 avbf1;             // packed attr of next tile (q==0 lanes)
  int s2, d2;              // in-flight ei of t+2
  float4 av2;              // in-flight attr of t+2 (q==0 lanes)
  {
    int ss = ei[t0 * TILE + e];
    int dd = ei[E_EDGES + t0 * TILE + e];
    unsigned prow0 = pack_rows(ss, dd);
    float4 av0;
    if (q == 0) av0 = ((const float4*)attr)[t0 * TILE + e];
    glds_tile(prow0, 0);
    __builtin_amdgcn_sched_barrier(0);
    int s1 = ei[tA * TILE + e];
    int d1 = ei[E_EDGES + tA * TILE + e];
    float4 av1;
    if (q == 0) av1 = ((const float4*)attr)[tA * TILE + e];
    s2 = ei[tB * TILE + e];
    d2 = ei[E_EDGES + tB * TILE + e];
    if (q == 0) av2 = ((const float4*)attr)[tB * TILE + e];
    if (q == 0) *(uint4*)(attrB + e * 8) = attr_pack(av0);
    prow1 = pack_rows(s1, d1);
    if (q == 0) avbf1 = attr_pack(av1);
    __builtin_amdgcn_sched_barrier(0);
    asm volatile("s_waitcnt vmcnt(0) lgkmcnt(0)" ::: "memory");
    __builtin_amdgcn_sched_barrier(0);
    __builtin_amdgcn_s_barrier();
    cfence();
  }

  int pp = 0;
  for (int tile = t0; ; ) {
    const int tnext = tile + grid;
    const bool more = tnext < NTILES;

    // ---- top: consume t+2 state, issue t+3 loads, stage t+1 (glds + attrB)
    if (more) {
      unsigned prow2 = pack_rows(s2, d2);
      uint4 avbf2;
      if (q == 0) avbf2 = attr_pack(av2);
      int tC = tile + 3 * grid; if (tC > NTILES - 1) tC = NTILES - 1;
      s2 = ei[tC * TILE + e];
      d2 = ei[E_EDGES + tC * TILE + e];
      if (q == 0) av2 = ((const float4*)attr)[tC * TILE + e];
      glds_tile(prow1, pp ^ 1);
      if (q == 0) *(uint4*)(attrB + (pp ^ 1) * 512 + e * 8) = avbf1;
      prow1 = prow2;
      avbf1 = avbf2;
    }
    __builtin_amdgcn_sched_barrier(0);

    // ---- MFMA on buffer pp
    const unsigned short* Ar = A + pp * (TILE * 128);
    const unsigned short* aB = attrB + pp * 512;

    floatx4 acc[2][4];
#pragma unroll
    for (int mt = 0; mt < 2; ++mt)
#pragma unroll
      for (int nt = 0; nt < 4; ++nt)
        acc[mt][nt] = (floatx4){0.f, 0.f, 0.f, 0.f};

#pragma unroll
    for (int kk = 0; kk < 4; ++kk) {
      shortx8 afr[2];
#pragma unroll
      for (int mt = 0; mt < 2; ++mt) {
        int r = eh * 32 + mt * 16 + l15;
        afr[mt] = *(const shortx8*)(Ar + r * 128 + (((kk * 4 + quad) ^ (r & 7)) << 3));
      }
#pragma unroll
      for (int mt = 0; mt < 2; ++mt)
#pragma unroll
        for (int nt = 0; nt < 4; ++nt)
          acc[mt][nt] = __builtin_amdgcn_mfma_f32_16x16x32_bf16(
              afr[mt], bfr[nt][kk], acc[mt][nt], 0, 0, 0);
    }
    {   // kk=4: attr+bias. A-side zero on quads 1-3 annihilates B garbage.
      shortx8 a4[2];
#pragma unroll
      for (int mt = 0; mt < 2; ++mt) {
        int r = eh * 32 + mt * 16 + l15;
        shortx8 v = (shortx8){0, 0, 0, 0, 0, 0, 0, 0};
        if (quad == 0) v = *(const shortx8*)(aB + r * 8);
        a4[mt] = v;
      }
#pragma unroll
      for (int mt = 0; mt < 2; ++mt)
#pragma unroll
        for (int nt = 0; nt < 4; ++nt)
          acc[mt][nt] = __builtin_amdgcn_mfma_f32_16x16x32_bf16(
              a4[mt], bfr4[nt], acc[mt][nt], 0, 0, 0);
    }

    // ---- epilogue for 'tile'
    float tpart[2][4];
    if (!OUT) {
      // C/D layout: col = lane&15 (channel), row = quad*4 + reg (edge)
#pragma unroll
      for (int nt = 0; nt < 4; ++nt) {
        float s = 0.f, qq = 0.f;
#pragma unroll
        for (int mt = 0; mt < 2; ++mt)
#pragma unroll
          for (int r = 0; r < 4; ++r) {
            float h = acc[mt][nt][r];
            s += h; qq += h * h;
          }
        ssum[nt] += s; ssq[nt] += qq;
      }
    } else {
#pragma unroll
      for (int mt = 0; mt < 2; ++mt)
#pragma unroll
        for (int r = 0; r < 4; ++r) {
          float t = 0.f;
#pragma unroll
          for (int nt = 0; nt < 4; ++nt) {
            float h = acc[mt][nt][r];
            float p = ea[nt] * h + ebb[nt];
            p = (p >= 0.f) ? p : 0.2f * p;
            t += p * ew2[nt];
          }
          t += __shfl_xor(t, 1);
          t += __shfl_xor(t, 2);
          t += __shfl_xor(t, 4);
          t += __shfl_xor(t, 8);   // t = sum over this wave's 64 channels
          tpart[mt][r] = t;
        }
      if (nh == 1 && l15 == 0) {
#pragma unroll
        for (int mt = 0; mt < 2; ++mt)
#pragma unroll
          for (int r = 0; r < 4; ++r)
            po[pp][eh * 32 + mt * 16 + quad * 4 + r] = tpart[mt][r];
      }
    }

    // ---- publish: drain glds (issued a full tile ago) + LDS writes, barrier
    if (more) {
      __builtin_amdgcn_sched_barrier(0);
      asm volatile("s_waitcnt vmcnt(0) lgkmcnt(0)" ::: "memory");
      __builtin_amdgcn_sched_barrier(0);
      __builtin_amdgcn_s_barrier();
      cfence();
    } else if (OUT) {
      asm volatile("s_waitcnt lgkmcnt(0)" ::: "memory");
      __builtin_amdgcn_s_barrier();
      cfence();
    }

    if (OUT && nh == 0 && l15 == 0) {
#pragma unroll
      for (int mt = 0; mt < 2; ++mt)
#pragma unroll
        for (int r = 0; r < 4; ++r) {
          int el = eh * 32 + mt * 16 + quad * 4 + r;
          out[tile * TILE + el] = tpart[mt][r] + po[pp][el] + b2v;
        }
    }

    if (!more) break;
    pp ^= 1;
    tile = tnext;
  }

  if (!OUT) {
#pragma unroll
    for (int nt = 0; nt < 4; ++nt) {
      float s = ssum[nt], qq = ssq[nt];
      s += __shfl_xor(s, 16); s += __shfl_xor(s, 32);
      qq += __shfl_xor(qq, 16); qq += __shfl_xor(qq, 32);
      if (quad == 0) {
        atomicAdd(&s_sum[nh * 64 + nt * 16 + l15], s);
        atomicAdd(&s_sq [nh * 64 + nt * 16 + l15], qq);
      }
    }
    __syncthreads();
    float* dstc = gstats + (blockIdx.x & (NSPREAD - 1)) * 2 * HCH;
    if (tid < HCH)          atomicAdd(&dstc[tid], s_sum[tid]);
    else if (tid < 2 * HCH) atomicAdd(&dstc[tid], s_sq[tid - HCH]);
  }
}

// -------------------------------------------------------------- launch ----
extern "C" void kernel_launch(void* const* d_in, const int* in_sizes, int n_in,
                              void* d_out, int out_size, void* d_ws, size_t ws_size,
                              hipStream_t stream) {
  const float* z     = (const float*)d_in[0];
  const float* attr  = (const float*)d_in[1];
  const float* W1    = (const float*)d_in[2];
  const float* b1    = (const float*)d_in[3];
  const float* gamma = (const float*)d_in[4];
  const float* beta  = (const float*)d_in[5];
  const float* W2    = (const float*)d_in[6];
  const float* b2    = (const float*)d_in[7];
  const int*   ei    = (const int*)d_in[8];
  float* out = (float*)d_out;

  char* ws = (char*)d_ws;
  unsigned short* zb  = (unsigned short*)ws;                 // 8,388,608 B
  unsigned short* w1t = (unsigned short*)(ws + 8388608);     //    34,816 B
  float* gstats       = (float*)(ws + 8423424);              //     8,192 B

  k_prep<<<ZBLK + 2, 256, 0, stream>>>(z, W1, b1, zb, w1t, gstats);
  k_gemm<false><<<GRID_GEMM, 256, 0, stream>>>(zb, w1t, ei, attr, gstats,
                                               gamma, beta, W2, b2, nullptr);
  k_gemm<true><<<GRID_GEMM, 256, 0, stream>>>(zb, w1t, ei, attr, gstats,
                                              gamma, beta, W2, b2, out);
}

// Round 4
// 243.498 us; speedup vs baseline: 1.3329x; 1.3329x over previous
//
#include <hip/hip_runtime.h>

#define E_EDGES   1000000
#define NNODES    2048
#define DLAT      64
#define HCH       128
#define KP        136            // w1t row stride in bf16 (global memory layout only)
#define TILE      64
#define NTILES    (E_EDGES / TILE)   // 15625 exact
#define NSPREAD   8
#define GRID_GEMM 512            // exactly 2 blocks/CU resident, single dispatch round
#define ZVEC      (32 * 2048 * 64 / 4)   // 1048576 float4s
#define ZBLK      2048

typedef short  shortx8 __attribute__((ext_vector_type(8)));
typedef float  floatx4 __attribute__((ext_vector_type(4)));

__device__ __forceinline__ unsigned short f2bf(float f) {
  union { float f; unsigned int u; } v; v.f = f;
  unsigned int r = (v.u + 0x7fffu + ((v.u >> 16) & 1u)) >> 16;
  return (unsigned short)r;
}

__device__ __forceinline__ void cfence() { asm volatile("" ::: "memory"); }

// pack attr floats -> [bf(a0),bf(a1),bf(a2),bf(a3),bf16(1.0),0,0,0] as uint4
__device__ __forceinline__ uint4 attr_pack(float4 a) {
  uint4 w;
  w.x = (unsigned)f2bf(a.x) | ((unsigned)f2bf(a.y) << 16);
  w.y = (unsigned)f2bf(a.z) | ((unsigned)f2bf(a.w) << 16);
  w.z = 0x3F80u;   // bf16(1.0) in low half (bias lane), 0 in high
  w.w = 0u;
  return w;
}

__device__ __forceinline__ unsigned pack_rows(int s, int d) {
  unsigned rs = (unsigned)s & 0xFFFFu;
  unsigned rd = (unsigned)(((s & ~(NNODES - 1)) | (d & (NNODES - 1)))) & 0xFFFFu; // dst uses src batch
  return rs | (rd << 16);
}

// ---------------------------------------------------------------- prep ----
__global__ void k_prep(const float* __restrict__ z, const float* __restrict__ W1,
                       const float* __restrict__ b1,
                       unsigned short* __restrict__ zb, unsigned short* __restrict__ w1t,
                       float* __restrict__ gstats) {
  int bid = blockIdx.x;
  if (bid < ZBLK) {
    const float4* z4 = (const float4*)z;
    ushort4* zb4 = (ushort4*)zb;
    for (int i = bid * 256 + threadIdx.x; i < ZVEC; i += ZBLK * 256) {
      float4 v = z4[i];
      ushort4 o;
      o.x = f2bf(v.x); o.y = f2bf(v.y); o.z = f2bf(v.z); o.w = f2bf(v.w);
      zb4[i] = o;
    }
  } else if (bid == ZBLK) {
    // W1T[n][k] = W1[k][n] for k<132, b1[n] at k=132, 0 for k in 133..135
    for (int idx = threadIdx.x; idx < 132 * HCH; idx += 256) {
      int k = idx >> 7, n = idx & 127;              // coalesced read of W1
      w1t[n * KP + k] = f2bf(W1[idx]);
    }
    for (int idx = threadIdx.x; idx < HCH * (KP - 132); idx += 256) {
      int n = idx / (KP - 132);
      int k = 132 + (idx - n * (KP - 132));
      w1t[n * KP + k] = (k == 132) ? f2bf(b1[n]) : (unsigned short)0;
    }
  } else {
    for (int i = threadIdx.x; i < NSPREAD * 2 * HCH; i += 256) gstats[i] = 0.f;
  }
}

// ---------------------------------------------------------------- gemm ----
// Depth-2 glds pipeline: triple-buffered A; glds for tile t+2 issued at top of
// iter t; publish uses COUNTED vmcnt (7 = 4 glds(t+2) + 3 reg loads) so the
// next tile's staging stays in flight across the barrier.
// 4 waves in 2x2: wave=(eh,nh): edges eh*32..+31, ch nh*64..+63.
template<bool OUT>
__global__ __launch_bounds__(256, 2)
void k_gemm(const unsigned short* __restrict__ zb,
            const unsigned short* __restrict__ w1t,
            const int* __restrict__ ei,
            const float* __restrict__ attr,
            float* __restrict__ gstats,
            const float* __restrict__ gamma,
            const float* __restrict__ beta,
            const float* __restrict__ W2,
            const float* __restrict__ b2,
            float* __restrict__ out) {
  __shared__ __align__(16) unsigned short A[3 * TILE * 128];     // 49152 B
  __shared__ __align__(16) unsigned short attrB[3 * TILE * 8];   //  3072 B
  __shared__ float s_sum[HCH], s_sq[HCH];
  __shared__ float po[2][TILE];

  const int tid  = threadIdx.x;
  const int lane = tid & 63;
  const int wave = tid >> 6;
  const int l15  = lane & 15;
  const int quad = lane >> 4;
  const int eh   = wave >> 1;
  const int nh   = wave & 1;
  const int e    = tid >> 2;     // this thread's own edge within tile
  const int q    = tid & 3;
  const int grid = GRID_GEMM;

  // stage one 64-edge tile into A[dst] via 4 global_load_lds per wave.
  // physical slot s of row e holds logical 16B chunk g = s ^ (e&7)
  // (linear LDS dest, pre-swizzled global source — guide rule 21).
  auto glds_tile = [&](unsigned prow, int dst) {
#pragma unroll
    for (int c = 0; c < 4; ++c) {
      unsigned p = (unsigned)__shfl((int)prow, c * 16 + ((lane >> 4) << 2));
      int e7 = (c * 4 + (lane >> 4)) & 7;
      int g  = (lane & 15) ^ e7;
      unsigned row = (g < 8) ? (p & 0xFFFFu) : (p >> 16);
      const unsigned short* ga = zb + ((size_t)row << 6) + ((unsigned)(g & 7) << 3);
      unsigned short* la = (unsigned short*)A + dst * (TILE * 128) + wave * 2048 + c * 512;
      __builtin_amdgcn_global_load_lds(
          (const __attribute__((address_space(1))) unsigned int*)ga,
          (__attribute__((address_space(3))) unsigned int*)la, 16, 0, 0);
    }
  };

  // ---- B fragments in registers
  shortx8 bfr[4][4], bfr4[4];
#pragma unroll
  for (int nt = 0; nt < 4; ++nt) {
    const unsigned short* bp = w1t + (nh * 64 + nt * 16 + l15) * KP;
#pragma unroll
    for (int kk = 0; kk < 4; ++kk)
      bfr[nt][kk] = *(const shortx8*)(bp + kk * 32 + quad * 8);
    bfr4[nt] = *(const shortx8*)(bp + 128);   // k=128..135 (attr rows + bias); A=0 on quads 1-3
  }

  float ea[4], ebb[4], ew2[4], b2v = 0.f;
  float ssum[4] = {0.f, 0.f, 0.f, 0.f}, ssq[4] = {0.f, 0.f, 0.f, 0.f};
  if (OUT) {
#pragma unroll
    for (int nt = 0; nt < 4; ++nt) {
      int c = nh * 64 + nt * 16 + l15;
      float S = 0.f, Q = 0.f;
#pragma unroll
      for (int i = 0; i < NSPREAD; ++i) {
        S += gstats[i * 2 * HCH + c];
        Q += gstats[i * 2 * HCH + HCH + c];
      }
      float mu   = S * (1.0f / (float)E_EDGES);
      float var  = Q * (1.0f / (float)E_EDGES) - mu * mu;
      float rstd = rsqrtf(var + 1e-5f);
      float a = gamma[c] * rstd;
      ea[nt]  = a;
      ebb[nt] = beta[c] - mu * a;
      ew2[nt] = W2[c];
    }
    b2v = b2[0];
  } else {
    if (tid < HCH) { s_sum[tid] = 0.f; s_sq[tid] = 0.f; }
  }

  // ---- prologue: fill depth-2 pipeline
  const int t0 = blockIdx.x;
  int tI1 = t0 + grid;     if (tI1 > NTILES - 1) tI1 = NTILES - 1;
  int tI2 = t0 + 2 * grid; if (tI2 > NTILES - 1) tI2 = NTILES - 1;
  int tI3 = t0 + 3 * grid; if (tI3 > NTILES - 1) tI3 = NTILES - 1;

  unsigned prowH;          // rows for the glds to issue NEXT iteration (tile t+2)
  uint4 avbfH;             // its packed attr (q==0 lanes)
  int s2, d2;              // in-flight ei (one more tile ahead)
  float4 av2;              // in-flight attr
  {
    // reg loads for t0..t2 (consumed below), then t3 (left in flight LAST)
    int sa = ei[t0 * TILE + e],  da = ei[E_EDGES + t0 * TILE + e];
    int sb = ei[tI1 * TILE + e], db = ei[E_EDGES + tI1 * TILE + e];
    int sc = ei[tI2 * TILE + e], dc = ei[E_EDGES + tI2 * TILE + e];
    float4 a0, a1, ah;
    if (q == 0) {
      a0 = ((const float4*)attr)[t0 * TILE + e];
      a1 = ((const float4*)attr)[tI1 * TILE + e];
      ah = ((const float4*)attr)[tI2 * TILE + e];
    }
    // consume t0..t2 (forces those loads; t3 not yet issued)
    unsigned p0 = pack_rows(sa, da);
    unsigned p1 = pack_rows(sb, db);
    prowH = pack_rows(sc, dc);
    uint4 ab0, ab1;
    if (q == 0) { ab0 = attr_pack(a0); ab1 = attr_pack(a1); avbfH = attr_pack(ah); }
    __builtin_amdgcn_sched_barrier(0);
    // issue t3 reg loads (stay in flight), then glds t0, glds t1
    s2 = ei[tI3 * TILE + e];
    d2 = ei[E_EDGES + tI3 * TILE + e];
    if (q == 0) av2 = ((const float4*)attr)[tI3 * TILE + e];
    __builtin_amdgcn_sched_barrier(0);
    glds_tile(p0, 0);
    if (q == 0) *(uint4*)(attrB + 0 * 512 + e * 8) = ab0;
    __builtin_amdgcn_sched_barrier(0);
    glds_tile(p1, 1);
    if (q == 0) *(uint4*)(attrB + 1 * 512 + e * 8) = ab1;
    __builtin_amdgcn_sched_barrier(0);
    // FIFO: [t3 loads x3][glds(t0) x4][glds(t1) x4] -> vmcnt(4) retires t3+glds(t0)
    asm volatile("s_waitcnt vmcnt(4) lgkmcnt(0)" ::: "memory");
    __builtin_amdgcn_sched_barrier(0);
    __builtin_amdgcn_s_barrier();
    cfence();
  }

  int pp = 0;   // buffer of current tile (mod 3)
  int sl = 0;   // po slot parity
  for (int tile = t0; ; ) {
    const int tnext = tile + grid;
    const bool more = tnext < NTILES;
    const bool st2  = (tile + 2 * grid) < NTILES;   // issue glds for t+2?

    // ---- top: consume in-flight regs, issue next reg loads, issue glds(t+2)
    if (more) {
      unsigned prow2 = pack_rows(s2, d2);            // waits loads issued 1 iter ago
      uint4 avbf2;
      if (q == 0) avbf2 = attr_pack(av2);
      __builtin_amdgcn_sched_barrier(0);
      int tC = tile + 4 * grid; if (tC > NTILES - 1) tC = NTILES - 1;
      s2 = ei[tC * TILE + e];
      d2 = ei[E_EDGES + tC * TILE + e];
      if (q == 0) av2 = ((const float4*)attr)[tC * TILE + e];
      __builtin_amdgcn_sched_barrier(0);
      if (st2) {
        int dst = pp + 2; if (dst >= 3) dst -= 3;
        glds_tile(prowH, dst);
        if (q == 0) *(uint4*)(attrB + dst * 512 + e * 8) = avbfH;
      }
      prowH = prow2;
      avbfH = avbf2;
    }
    __builtin_amdgcn_sched_barrier(0);

    // ---- MFMA on buffer pp
    const unsigned short* Ar = A + pp * (TILE * 128);
    const unsigned short* aB = attrB + pp * 512;

    floatx4 acc[2][4];
#pragma unroll
    for (int mt = 0; mt < 2; ++mt)
#pragma unroll
      for (int nt = 0; nt < 4; ++nt)
        acc[mt][nt] = (floatx4){0.f, 0.f, 0.f, 0.f};

#pragma unroll
    for (int kk = 0; kk < 4; ++kk) {
      shortx8 afr[2];
#pragma unroll
      for (int mt = 0; mt < 2; ++mt) {
        int r = eh * 32 + mt * 16 + l15;
        afr[mt] = *(const shortx8*)(Ar + r * 128 + (((kk * 4 + quad) ^ (r & 7)) << 3));
      }
#pragma unroll
      for (int mt = 0; mt < 2; ++mt)
#pragma unroll
        for (int nt = 0; nt < 4; ++nt)
          acc[mt][nt] = __builtin_amdgcn_mfma_f32_16x16x32_bf16(
              afr[mt], bfr[nt][kk], acc[mt][nt], 0, 0, 0);
    }
    {   // kk=4: attr+bias. A-side zero on quads 1-3 annihilates B garbage.
      shortx8 a4[2];
#pragma unroll
      for (int mt = 0; mt < 2; ++mt) {
        int r = eh * 32 + mt * 16 + l15;
        shortx8 v = (shortx8){0, 0, 0, 0, 0, 0, 0, 0};
        if (quad == 0) v = *(const shortx8*)(aB + r * 8);
        a4[mt] = v;
      }
#pragma unroll
      for (int mt = 0; mt < 2; ++mt)
#pragma unroll
        for (int nt = 0; nt < 4; ++nt)
          acc[mt][nt] = __builtin_amdgcn_mfma_f32_16x16x32_bf16(
              a4[mt], bfr4[nt], acc[mt][nt], 0, 0, 0);
    }

    // ---- epilogue for 'tile'
    float tpart[2][4];
    if (!OUT) {
      // C/D layout: col = lane&15 (channel), row = quad*4 + reg (edge)
#pragma unroll
      for (int nt = 0; nt < 4; ++nt) {
        float s = 0.f, qq = 0.f;
#pragma unroll
        for (int mt = 0; mt < 2; ++mt)
#pragma unroll
          for (int r = 0; r < 4; ++r) {
            float h = acc[mt][nt][r];
            s += h; qq += h * h;
          }
        ssum[nt] += s; ssq[nt] += qq;
      }
    } else {
#pragma unroll
      for (int mt = 0; mt < 2; ++mt)
#pragma unroll
        for (int r = 0; r < 4; ++r) {
          float t = 0.f;
#pragma unroll
          for (int nt = 0; nt < 4; ++nt) {
            float h = acc[mt][nt][r];
            float p = ea[nt] * h + ebb[nt];
            p = (p >= 0.f) ? p : 0.2f * p;
            t += p * ew2[nt];
          }
          t += __shfl_xor(t, 1);
          t += __shfl_xor(t, 2);
          t += __shfl_xor(t, 4);
          t += __shfl_xor(t, 8);   // t = sum over this wave's 64 channels
          tpart[mt][r] = t;
        }
      if (nh == 1 && l15 == 0) {
#pragma unroll
        for (int mt = 0; mt < 2; ++mt)
#pragma unroll
          for (int r = 0; r < 4; ++r)
            po[sl][eh * 32 + mt * 16 + quad * 4 + r] = tpart[mt][r];
      }
    }

    // ---- publish: retire glds(t+1) only (counted vmcnt, never 0)
    if (more) {
      __builtin_amdgcn_sched_barrier(0);
      if (st2) asm volatile("s_waitcnt vmcnt(7) lgkmcnt(0)" ::: "memory");
      else     asm volatile("s_waitcnt vmcnt(3) lgkmcnt(0)" ::: "memory");
      __builtin_amdgcn_sched_barrier(0);
      __builtin_amdgcn_s_barrier();
      cfence();
    } else if (OUT) {
      asm volatile("s_waitcnt lgkmcnt(0)" ::: "memory");
      __builtin_amdgcn_s_barrier();
      cfence();
    }

    if (OUT && nh == 0 && l15 == 0) {
#pragma unroll
      for (int mt = 0; mt < 2; ++mt)
#pragma unroll
        for (int r = 0; r < 4; ++r) {
          int el = eh * 32 + mt * 16 + quad * 4 + r;
          out[tile * TILE + el] = tpart[mt][r] + po[sl][el] + b2v;
        }
    }

    if (!more) break;
    pp = (pp == 2) ? 0 : pp + 1;
    sl ^= 1;
    tile = tnext;
  }

  if (!OUT) {
#pragma unroll
    for (int nt = 0; nt < 4; ++nt) {
      float s = ssum[nt], qq = ssq[nt];
      s += __shfl_xor(s, 16); s += __shfl_xor(s, 32);
      qq += __shfl_xor(qq, 16); qq += __shfl_xor(qq, 32);
      if (quad == 0) {
        atomicAdd(&s_sum[nh * 64 + nt * 16 + l15], s);
        atomicAdd(&s_sq [nh * 64 + nt * 16 + l15], qq);
      }
    }
    __syncthreads();
    float* dstc = gstats + (blockIdx.x & (NSPREAD - 1)) * 2 * HCH;
    if (tid < HCH)          atomicAdd(&dstc[tid], s_sum[tid]);
    else if (tid < 2 * HCH) atomicAdd(&dstc[tid], s_sq[tid - HCH]);
  }
}

// -------------------------------------------------------------- launch ----
extern "C" void kernel_launch(void* const* d_in, const int* in_sizes, int n_in,
                              void* d_out, int out_size, void* d_ws, size_t ws_size,
                              hipStream_t stream) {
  const float* z     = (const float*)d_in[0];
  const float* attr  = (const float*)d_in[1];
  const float* W1    = (const float*)d_in[2];
  const float* b1    = (const float*)d_in[3];
  const float* gamma = (const float*)d_in[4];
  const float* beta  = (const float*)d_in[5];
  const float* W2    = (const float*)d_in[6];
  const float* b2    = (const float*)d_in[7];
  const int*   ei    = (const int*)d_in[8];
  float* out = (float*)d_out;

  char* ws = (char*)d_ws;
  unsigned short* zb  = (unsigned short*)ws;                 // 8,388,608 B
  unsigned short* w1t = (unsigned short*)(ws + 8388608);     //    34,816 B
  float* gstats       = (float*)(ws + 8423424);              //     8,192 B

  k_prep<<<ZBLK + 2, 256, 0, stream>>>(z, W1, b1, zb, w1t, gstats);
  k_gemm<false><<<GRID_GEMM, 256, 0, stream>>>(zb, w1t, ei, attr, gstats,
                                               gamma, beta, W2, b2, nullptr);
  k_gemm<true><<<GRID_GEMM, 256, 0, stream>>>(zb, w1t, ei, attr, gstats,
                                              gamma, beta, W2, b2, out);
}